// Round 12
// baseline (204.553 us; speedup 1.0000x reference)
//
#include <hip/hip_runtime.h>

#define NDIM 28
#define SPAT 784            // 28*28
#define STRIPS 196          // float4 strips per plane
#define NB 256
#define CIN 256
#define COUT 256
#define SCH 4               // Cin split factor
#define CPC (CIN / SCH)     // 64 planes per chunk
#define XSC 36              // halo'd plane row stride (floats) = 9 float4
#define PLQ 270             // float4 per halo'd plane (30*36/4)

typedef float f4v __attribute__((ext_vector_type(4)));

// Kernel 1 (IDENTICAL to R6, proven 7.04 TB/s): block = (b, chunk), 1024 blocks.
__global__ __launch_bounds__(256) void k_sum(const float* __restrict__ x,
                                             float* __restrict__ pbuf) {
    int bid = blockIdx.x;          // 0..1023
    int b     = bid >> 2;
    int chunk = bid & 3;
    int t = threadIdx.x;
    if (t >= STRIPS) return;

    const float4* xp = (const float4*)x
        + ((size_t)b * CIN + (size_t)chunk * CPC) * STRIPS + t;
    float ax = 0.f, ay = 0.f, az = 0.f, aw = 0.f;
    #pragma unroll 16
    for (int c = 0; c < CPC; ++c) {
        float4 v = xp[c * STRIPS];
        ax += v.x; ay += v.y; az += v.z; aw += v.w;
    }
    ((float4*)pbuf)[((size_t)b * SCH + chunk) * STRIPS + t] = make_float4(ax, ay, az, aw);
}

// Kernel 2: fold 4 partials -> global halo'd plane xsph[b][30][36] (1.1 MB, L2-hot).
__global__ __launch_bounds__(256) void k_combine(const float* __restrict__ pbuf,
                                                 float* __restrict__ xsph) {
    int b = blockIdx.x;
    int t = threadIdx.x;
    if (t >= STRIPS) return;

    const float4* pp = (const float4*)pbuf + (size_t)b * SCH * STRIPS + t;
    float4 a = pp[0];
    #pragma unroll
    for (int c = 1; c < SCH; ++c) {
        float4 v = pp[c * STRIPS];
        a.x += v.x; a.y += v.y; a.z += v.z; a.w += v.w;
    }
    int i = t / 7, q = t % 7;
    float* base = xsph + (size_t)b * (30 * XSC);
    *(float4*)(base + i * XSC + q * 4) = a;
    if (q == 0)                          // col halo: cols 28,29 = cols 0,1
        *(float4*)(base + i * XSC + 28) = a;
    if (i < 2) {                         // row halo: rows 28,29 = rows 0,1
        *(float4*)(base + (i + 28) * XSC + q * 4) = a;
        if (q == 0)
            *(float4*)(base + (i + 28) * XSC + 28) = a;
    }
}

// Kernel 3: co-major conv. Block = co (256 blocks, 1/CU); iterate b serially.
// At step b ALL blocks write inside the same 803 KB window out[b][*][*] ->
// chip-wide sliding write window (fill-kernel regime), PLAIN stores.
// Plane double-buffered through LDS; one barrier per iter.
__global__ __launch_bounds__(256) void k_convT(const float* __restrict__ xsph,
                                               const float* __restrict__ w,
                                               float* __restrict__ out) {
    __shared__ float buf[2][30 * XSC];

    const int co = blockIdx.x;
    const int t  = threadIdx.x;

    // filter, block-uniform -> s_loads; f[3a+c] = w0[co,2-a,2-c]
    const float* wp = w + (size_t)co * (CIN * 9);
    float f[9];
    #pragma unroll
    for (int k = 0; k < 9; ++k) f[k] = wp[8 - k];

    const int i  = t / 7;          // compute coords (t<196)
    const int js = (t % 7) * 4;
    const int r  = t >> 3;         // stage coords (t<240): row, float4-col
    const int c4 = t & 7;
    const f4v* gp = (const f4v*)xsph;

    // prologue: stage plane 0 into buf[0]
    if (t < 240)
        *(f4v*)&buf[0][r * XSC + c4 * 4] = gp[0 * PLQ + r * 9 + c4];

    for (int b = 0; b < NB; ++b) {
        const int cur = b & 1;

        f4v pre;
        const bool do_pre = (b + 1 < NB) && (t < 240);
        if (do_pre)                         // issue next-plane load early
            pre = gp[(size_t)(b + 1) * PLQ + r * 9 + c4];

        __syncthreads();                    // buf[cur] staged; buf[cur^1] free

        if (do_pre)
            *(f4v*)&buf[cur ^ 1][r * XSC + c4 * 4] = pre;

        if (t < STRIPS) {
            float W[3][8];
            #pragma unroll
            for (int a = 0; a < 3; ++a) {
                float4 lo = *(const float4*)&buf[cur][(i + a) * XSC + js];
                float4 hi = *(const float4*)&buf[cur][(i + a) * XSC + js + 4];
                W[a][0] = lo.x; W[a][1] = lo.y; W[a][2] = lo.z; W[a][3] = lo.w;
                W[a][4] = hi.x; W[a][5] = hi.y; W[a][6] = hi.z; W[a][7] = hi.w;
            }
            float o0 = 0.f, o1 = 0.f, o2 = 0.f, o3 = 0.f;
            #pragma unroll
            for (int a = 0; a < 3; ++a) {
                #pragma unroll
                for (int c = 0; c < 3; ++c) {
                    float fv = f[3 * a + c];
                    o0 += fv * W[a][0 + c];
                    o1 += fv * W[a][1 + c];
                    o2 += fv * W[a][2 + c];
                    o3 += fv * W[a][3 + c];
                }
            }
            *(float4*)(out + ((size_t)b * COUT + co) * SPAT + i * NDIM + js)
                = make_float4(o0, o1, o2, o3);
        }
    }
}

extern "C" void kernel_launch(void* const* d_in, const int* in_sizes, int n_in,
                              void* d_out, int out_size, void* d_ws, size_t ws_size,
                              hipStream_t stream) {
    const float* x = (const float*)d_in[0];       // (256,256,28,28) f32
    const float* w = (const float*)d_in[1];       // (256,256,3,3) f32
    float* out = (float*)d_out;                   // (256,256,28,28) f32

    float* pbuf = (float*)d_ws;                         // 256*4*784 f32 = 3.2 MB
    float* xsph = pbuf + (size_t)NB * SCH * SPAT;       // 256*30*36 f32 = 1.1 MB

    k_sum    <<<NB * SCH, 256, 0, stream>>>(x, pbuf);   // 1024 blocks, 4/CU
    k_combine<<<NB,       256, 0, stream>>>(pbuf, xsph);// 256 blocks
    k_convT  <<<NB,       256, 0, stream>>>(xsph, w, out); // 256 blocks, 1/CU
}

// Round 13
// 173.057 us; speedup vs baseline: 1.1820x; 1.1820x over previous
//
#include <hip/hip_runtime.h>

#define NDIM 28
#define SPAT 784            // 28*28
#define STRIPS 196          // float4 strips per plane
#define NB 256
#define CIN 256
#define COUT 256
#define SCH 4               // Cin split factor
#define CPC (CIN / SCH)     // 64 planes per chunk
#define XSC 36              // halo'd plane row stride (floats)
#define PLF (30 * XSC)      // floats per halo'd plane = 1080

typedef float f4v __attribute__((ext_vector_type(4)));

// Kernel 1 (IDENTICAL to R6, proven 7.04 TB/s): block = (b, chunk), 1024 blocks.
__global__ __launch_bounds__(256) void k_sum(const float* __restrict__ x,
                                             float* __restrict__ pbuf) {
    int bid = blockIdx.x;          // 0..1023
    int b     = bid >> 2;
    int chunk = bid & 3;
    int t = threadIdx.x;
    if (t >= STRIPS) return;

    const float4* xp = (const float4*)x
        + ((size_t)b * CIN + (size_t)chunk * CPC) * STRIPS + t;
    float ax = 0.f, ay = 0.f, az = 0.f, aw = 0.f;
    #pragma unroll 16
    for (int c = 0; c < CPC; ++c) {
        float4 v = xp[c * STRIPS];
        ax += v.x; ay += v.y; az += v.z; aw += v.w;
    }
    ((float4*)pbuf)[((size_t)b * SCH + chunk) * STRIPS + t] = make_float4(ax, ay, az, aw);
}

// Kernel 2: fold 4 partials -> global halo'd planes xsph[b][30][36] (1.1 MB, L2-hot).
__global__ __launch_bounds__(256) void k_combine(const float* __restrict__ pbuf,
                                                 float* __restrict__ xsph) {
    int b = blockIdx.x;
    int t = threadIdx.x;
    if (t >= STRIPS) return;

    const float4* pp = (const float4*)pbuf + (size_t)b * SCH * STRIPS + t;
    float4 a = pp[0];
    #pragma unroll
    for (int c = 1; c < SCH; ++c) {
        float4 v = pp[c * STRIPS];
        a.x += v.x; a.y += v.y; a.z += v.z; a.w += v.w;
    }
    int i = t / 7, q = t % 7;
    float* base = xsph + (size_t)b * PLF;
    *(float4*)(base + i * XSC + q * 4) = a;
    if (q == 0)                          // col halo: cols 28,29 = cols 0,1
        *(float4*)(base + i * XSC + 28) = a;
    if (i < 2) {                         // row halo: rows 28,29 = rows 0,1
        *(float4*)(base + (i + 28) * XSC + q * 4) = a;
        if (q == 0)
            *(float4*)(base + (i + 28) * XSC + 28) = a;
    }
}

// Kernel 3: co-major conv, NO barriers, NO LDS. Block = co (256 = 1/CU);
// iterate b serially; window read straight from L1/L2-resident xsph with a
// 1-plane register software pipeline; PLAIN stores land in a chip-wide
// sliding ~803 KB window (fill-kernel regime).
__global__ __launch_bounds__(256) void k_convT(const float* __restrict__ xsph,
                                               const float* __restrict__ w,
                                               float* __restrict__ out) {
    const int co = blockIdx.x;
    const int t  = threadIdx.x;
    if (t >= STRIPS) return;

    const float* wp = w + (size_t)co * (CIN * 9);   // block-uniform -> s_loads
    float f[9];
    #pragma unroll
    for (int k = 0; k < 9; ++k) f[k] = wp[8 - k];   // f[3a+c] = w0[co,2-a,2-c]

    const int i  = t / 7;
    const int js = (t % 7) * 4;
    const float* base = xsph + i * XSC + js;        // row i, col js of plane 0

    float4 cl0, cl1, cl2, ch0, ch1, ch2;            // current window regs
    {
        const float* q = base;
        cl0 = *(const float4*)q;             ch0 = *(const float4*)(q + 4);
        cl1 = *(const float4*)(q + XSC);     ch1 = *(const float4*)(q + XSC + 4);
        cl2 = *(const float4*)(q + 2 * XSC); ch2 = *(const float4*)(q + 2 * XSC + 4);
    }

    size_t ob = (size_t)co * SPAT + i * NDIM + js;

    #pragma unroll 2
    for (int b = 0; b < NB; ++b) {
        float4 nl0 = cl0, nl1 = cl1, nl2 = cl2, nh0 = ch0, nh1 = ch1, nh2 = ch2;
        if (b + 1 < NB) {                   // prefetch next plane's window
            const float* q = base + (size_t)(b + 1) * PLF;
            nl0 = *(const float4*)q;             nh0 = *(const float4*)(q + 4);
            nl1 = *(const float4*)(q + XSC);     nh1 = *(const float4*)(q + XSC + 4);
            nl2 = *(const float4*)(q + 2 * XSC); nh2 = *(const float4*)(q + 2 * XSC + 4);
        }

        float W[3][8];
        W[0][0] = cl0.x; W[0][1] = cl0.y; W[0][2] = cl0.z; W[0][3] = cl0.w;
        W[0][4] = ch0.x; W[0][5] = ch0.y; W[0][6] = ch0.z; W[0][7] = ch0.w;
        W[1][0] = cl1.x; W[1][1] = cl1.y; W[1][2] = cl1.z; W[1][3] = cl1.w;
        W[1][4] = ch1.x; W[1][5] = ch1.y; W[1][6] = ch1.z; W[1][7] = ch1.w;
        W[2][0] = cl2.x; W[2][1] = cl2.y; W[2][2] = cl2.z; W[2][3] = cl2.w;
        W[2][4] = ch2.x; W[2][5] = ch2.y; W[2][6] = ch2.z; W[2][7] = ch2.w;

        float o0 = 0.f, o1 = 0.f, o2 = 0.f, o3 = 0.f;
        #pragma unroll
        for (int a = 0; a < 3; ++a) {
            #pragma unroll
            for (int c = 0; c < 3; ++c) {
                float fv = f[3 * a + c];
                o0 += fv * W[a][0 + c];
                o1 += fv * W[a][1 + c];
                o2 += fv * W[a][2 + c];
                o3 += fv * W[a][3 + c];
            }
        }
        *(float4*)(out + ob + (size_t)b * (COUT * SPAT)) = make_float4(o0, o1, o2, o3);

        cl0 = nl0; ch0 = nh0; cl1 = nl1; ch1 = nh1; cl2 = nl2; ch2 = nh2;
    }
}

extern "C" void kernel_launch(void* const* d_in, const int* in_sizes, int n_in,
                              void* d_out, int out_size, void* d_ws, size_t ws_size,
                              hipStream_t stream) {
    const float* x = (const float*)d_in[0];       // (256,256,28,28) f32
    const float* w = (const float*)d_in[1];       // (256,256,3,3) f32
    float* out = (float*)d_out;                   // (256,256,28,28) f32

    float* pbuf = (float*)d_ws;                         // 256*4*784 f32 = 3.2 MB
    float* xsph = pbuf + (size_t)NB * SCH * SPAT;       // 256*1080 f32 = 1.1 MB

    k_sum    <<<NB * SCH, 256, 0, stream>>>(x, pbuf);      // 1024 blocks, 4/CU
    k_combine<<<NB,       256, 0, stream>>>(pbuf, xsph);   // 256 blocks
    k_convT  <<<COUT,     256, 0, stream>>>(xsph, w, out); // 256 blocks, 1/CU
}

// Round 14
// 139.065 us; speedup vs baseline: 1.4709x; 1.2444x over previous
//
#include <hip/hip_runtime.h>

#define NDIM 28
#define SPAT 784            // 28*28
#define STRIPS 196          // float4 strips per plane
#define NB 256
#define CIN 256
#define COUT 256
#define SCH 4               // Cin split factor
#define CPC (CIN / SCH)     // 64 planes per chunk
#define XSC 36              // halo'd plane row stride (floats)
#define PLF (30 * XSC)      // floats per halo'd plane = 1080

typedef float f4v __attribute__((ext_vector_type(4)));

// Kernel 1 (IDENTICAL to R6, proven 7.04 TB/s): block = (b, chunk), 1024 blocks.
__global__ __launch_bounds__(256) void k_sum(const float* __restrict__ x,
                                             float* __restrict__ pbuf) {
    int bid = blockIdx.x;          // 0..1023
    int b     = bid >> 2;
    int chunk = bid & 3;
    int t = threadIdx.x;
    if (t >= STRIPS) return;

    const float4* xp = (const float4*)x
        + ((size_t)b * CIN + (size_t)chunk * CPC) * STRIPS + t;
    float ax = 0.f, ay = 0.f, az = 0.f, aw = 0.f;
    #pragma unroll 16
    for (int c = 0; c < CPC; ++c) {
        float4 v = xp[c * STRIPS];
        ax += v.x; ay += v.y; az += v.z; aw += v.w;
    }
    ((float4*)pbuf)[((size_t)b * SCH + chunk) * STRIPS + t] = make_float4(ax, ay, az, aw);
}

// Kernel 2 (IDENTICAL to R12): fold 4 partials -> halo'd planes xsph[b][30][36].
__global__ __launch_bounds__(256) void k_combine(const float* __restrict__ pbuf,
                                                 float* __restrict__ xsph) {
    int b = blockIdx.x;
    int t = threadIdx.x;
    if (t >= STRIPS) return;

    const float4* pp = (const float4*)pbuf + (size_t)b * SCH * STRIPS + t;
    float4 a = pp[0];
    #pragma unroll
    for (int c = 1; c < SCH; ++c) {
        float4 v = pp[c * STRIPS];
        a.x += v.x; a.y += v.y; a.z += v.z; a.w += v.w;
    }
    int i = t / 7, q = t % 7;
    float* base = xsph + (size_t)b * PLF;
    *(float4*)(base + i * XSC + q * 4) = a;
    if (q == 0)                          // col halo: cols 28,29 = cols 0,1
        *(float4*)(base + i * XSC + 28) = a;
    if (i < 2) {                         // row halo: rows 28,29 = rows 0,1
        *(float4*)(base + (i + 28) * XSC + q * 4) = a;
        if (q == 0)
            *(float4*)(base + (i + 28) * XSC + 28) = a;
    }
}

// Kernel 3: grid-stride conv in EXACT memory order (fill-kernel mimicry).
// task = b*256 + co -> out address task*3136B; 2048 blocks x 256 thr =
// 32 waves/CU; active tasks span a ~6.4 MB sliding write window; PLAIN stores.
// Read set: one 4.3 KB xsph plane shared by 256 consecutive tasks (L1-hot).
__global__ __launch_bounds__(256) void k_conv_gs(const float* __restrict__ xsph,
                                                 const float* __restrict__ w,
                                                 float* __restrict__ out) {
    const int t  = threadIdx.x;
    const int i  = t / 7;
    const int js = (t % 7) * 4;

    for (int task = blockIdx.x; task < NB * COUT; task += 2048) {
        const int b  = task >> 8;
        const int co = task & 255;

        if (t < STRIPS) {
            const float* q = xsph + (size_t)b * PLF + i * XSC + js;
            float4 l0 = *(const float4*)q;
            float4 h0 = *(const float4*)(q + 4);
            float4 l1 = *(const float4*)(q + XSC);
            float4 h1 = *(const float4*)(q + XSC + 4);
            float4 l2 = *(const float4*)(q + 2 * XSC);
            float4 h2 = *(const float4*)(q + 2 * XSC + 4);

            const float* wp = w + (size_t)co * (CIN * 9);   // block-uniform -> s_loads
            float f[9];
            #pragma unroll
            for (int k = 0; k < 9; ++k) f[k] = wp[8 - k];   // f[3a+c] = w0[co,2-a,2-c]

            float W[3][8];
            W[0][0] = l0.x; W[0][1] = l0.y; W[0][2] = l0.z; W[0][3] = l0.w;
            W[0][4] = h0.x; W[0][5] = h0.y; W[0][6] = h0.z; W[0][7] = h0.w;
            W[1][0] = l1.x; W[1][1] = l1.y; W[1][2] = l1.z; W[1][3] = l1.w;
            W[1][4] = h1.x; W[1][5] = h1.y; W[1][6] = h1.z; W[1][7] = h1.w;
            W[2][0] = l2.x; W[2][1] = l2.y; W[2][2] = l2.z; W[2][3] = l2.w;
            W[2][4] = h2.x; W[2][5] = h2.y; W[2][6] = h2.z; W[2][7] = h2.w;

            float o0 = 0.f, o1 = 0.f, o2 = 0.f, o3 = 0.f;
            #pragma unroll
            for (int a = 0; a < 3; ++a) {
                #pragma unroll
                for (int c = 0; c < 3; ++c) {
                    float fv = f[3 * a + c];
                    o0 += fv * W[a][0 + c];
                    o1 += fv * W[a][1 + c];
                    o2 += fv * W[a][2 + c];
                    o3 += fv * W[a][3 + c];
                }
            }
            *(float4*)(out + (size_t)task * SPAT + i * NDIM + js)
                = make_float4(o0, o1, o2, o3);
        }
    }
}

extern "C" void kernel_launch(void* const* d_in, const int* in_sizes, int n_in,
                              void* d_out, int out_size, void* d_ws, size_t ws_size,
                              hipStream_t stream) {
    const float* x = (const float*)d_in[0];       // (256,256,28,28) f32
    const float* w = (const float*)d_in[1];       // (256,256,3,3) f32
    float* out = (float*)d_out;                   // (256,256,28,28) f32

    float* pbuf = (float*)d_ws;                         // 256*4*784 f32 = 3.2 MB
    float* xsph = pbuf + (size_t)NB * SCH * SPAT;       // 256*1080 f32 = 1.1 MB

    k_sum    <<<NB * SCH, 256, 0, stream>>>(x, pbuf);      // 1024 blocks, 4/CU
    k_combine<<<NB,       256, 0, stream>>>(pbuf, xsph);   // 256 blocks
    k_conv_gs<<<2048,     256, 0, stream>>>(xsph, w, out); // 8 blocks/CU, linear order
}

// Round 15
// 79.359 us; speedup vs baseline: 2.5776x; 1.7524x over previous
//
#include <hip/hip_runtime.h>

#define NDIM 28
#define SPAT 784            // 28*28
#define STRIPS 196          // float4 strips per plane
#define NB 256
#define CIN 256
#define COUT 256
#define SCH 8               // Cin split: 32 planes per chunk (fine-grain for mix TLP)
#define CPC (CIN / SCH)
#define XSC 36              // LDS halo'd plane row stride (floats)
#define QB 64               // batches per pipeline quarter

typedef float f4v __attribute__((ext_vector_type(4)));

// ---- sum body: 32-plane partial -> pbuf[b][chunk][196] ----
__device__ __forceinline__ void dev_sum(const float* __restrict__ x,
                                        float* __restrict__ pbuf,
                                        int b, int chunk, int t) {
    if (t >= STRIPS) return;
    const float4* xp = (const float4*)x
        + ((size_t)b * CIN + (size_t)chunk * CPC) * STRIPS + t;
    float ax = 0.f, ay = 0.f, az = 0.f, aw = 0.f;
    #pragma unroll 16
    for (int c = 0; c < CPC; ++c) {
        float4 v = xp[c * STRIPS];
        ax += v.x; ay += v.y; az += v.z; aw += v.w;
    }
    ((float4*)pbuf)[((size_t)b * SCH + chunk) * STRIPS + t] = make_float4(ax, ay, az, aw);
}

// ---- conv body: fold 8 partials -> LDS halo'd plane -> 32 co, nt stores ----
__device__ __forceinline__ void dev_conv(const float* __restrict__ pbuf,
                                         const float* __restrict__ w,
                                         float* __restrict__ out,
                                         float* xs, int b, int cg, int t) {
    if (t < STRIPS) {
        const float4* pp = (const float4*)pbuf + (size_t)b * SCH * STRIPS + t;
        float4 a = pp[0];
        #pragma unroll
        for (int c = 1; c < SCH; ++c) {
            float4 v = pp[c * STRIPS];
            a.x += v.x; a.y += v.y; a.z += v.z; a.w += v.w;
        }
        int i = t / 7, q = t % 7;
        *(float4*)&xs[i * XSC + q * 4] = a;
        if (q == 0)                          // col halo
            *(float4*)&xs[i * XSC + 28] = a;
        if (i < 2) {                         // row halo
            *(float4*)&xs[(i + 28) * XSC + q * 4] = a;
            if (q == 0)
                *(float4*)&xs[(i + 28) * XSC + 28] = a;
        }
    }
    __syncthreads();

    if (t >= STRIPS) return;
    int i  = t / 7;
    int js = (t % 7) * 4;

    float W[3][8];
    #pragma unroll
    for (int a = 0; a < 3; ++a) {
        float4 lo = *(const float4*)&xs[(i + a) * XSC + js];
        float4 hi = *(const float4*)&xs[(i + a) * XSC + js + 4];
        W[a][0] = lo.x; W[a][1] = lo.y; W[a][2] = lo.z; W[a][3] = lo.w;
        W[a][4] = hi.x; W[a][5] = hi.y; W[a][6] = hi.z; W[a][7] = hi.w;
    }

    size_t ob = ((size_t)b * COUT + (size_t)cg * 32) * SPAT + i * NDIM + js;

    #pragma unroll 4
    for (int cl = 0; cl < 32; ++cl) {
        const float* wp = w + (size_t)(cg * 32 + cl) * (CIN * 9);
        float o0 = 0.f, o1 = 0.f, o2 = 0.f, o3 = 0.f;
        #pragma unroll
        for (int a = 0; a < 3; ++a) {
            #pragma unroll
            for (int c = 0; c < 3; ++c) {
                float fv = wp[8 - 3 * a - c];   // w0[co, 2-a, 2-c]
                o0 += fv * W[a][0 + c];
                o1 += fv * W[a][1 + c];
                o2 += fv * W[a][2 + c];
                o3 += fv * W[a][3 + c];
            }
        }
        f4v o = {o0, o1, o2, o3};
        __builtin_nontemporal_store(o, (f4v*)(out + ob + (size_t)cl * SPAT));
    }
}

// ends: sum-only quarter (512 blocks: 64 b x 8 chunks)
__global__ __launch_bounds__(256) void k_sumq(const float* __restrict__ x,
                                              float* __restrict__ pbuf, int b0) {
    dev_sum(x, pbuf, b0 + (blockIdx.x >> 3), blockIdx.x & 7, threadIdx.x);
}

// ends: conv-only quarter (512 blocks: 64 b x 8 cogroups)
__global__ __launch_bounds__(256) void k_convq(const float* __restrict__ pbuf,
                                               const float* __restrict__ w,
                                               float* __restrict__ out, int b0) {
    __shared__ float xs[30 * XSC];
    dev_conv(pbuf, w, out, xs, b0 + (blockIdx.x >> 3), blockIdx.x & 7, threadIdx.x);
}

// mixed: 1024 blocks (4/CU, 16 waves/CU). Parity-interleaved: odd = sum quarter
// bs0 (reads), even = conv quarter bc0 (nt writes). Each CU carries ~2 of each.
__global__ __launch_bounds__(256) void k_mix(const float* __restrict__ x,
                                             float* __restrict__ pbuf,
                                             const float* __restrict__ w,
                                             float* __restrict__ out,
                                             int bs0, int bc0) {
    __shared__ float xs[30 * XSC];
    int bid = blockIdx.x;
    int idx = bid >> 1;                 // 0..511
    if (bid & 1) {
        dev_sum(x, pbuf, bs0 + (idx >> 3), idx & 7, threadIdx.x);
    } else {
        dev_conv(pbuf, w, out, xs, bc0 + (idx >> 3), idx & 7, threadIdx.x);
    }
}

extern "C" void kernel_launch(void* const* d_in, const int* in_sizes, int n_in,
                              void* d_out, int out_size, void* d_ws, size_t ws_size,
                              hipStream_t stream) {
    const float* x = (const float*)d_in[0];       // (256,256,28,28) f32
    const float* w = (const float*)d_in[1];       // (256,256,3,3) f32
    float* out = (float*)d_out;                   // (256,256,28,28) f32
    float* pbuf = (float*)d_ws;                   // 256*8*784 f32 = 6.4 MB

    k_sumq <<< 512, 256, 0, stream>>>(x, pbuf, 0);
    k_mix  <<<1024, 256, 0, stream>>>(x, pbuf, w, out, 1 * QB, 0 * QB);
    k_mix  <<<1024, 256, 0, stream>>>(x, pbuf, w, out, 2 * QB, 1 * QB);
    k_mix  <<<1024, 256, 0, stream>>>(x, pbuf, w, out, 3 * QB, 2 * QB);
    k_convq<<< 512, 256, 0, stream>>>(pbuf, w, out, 3 * QB);
}

// Round 16
// 74.399 us; speedup vs baseline: 2.7494x; 1.0667x over previous
//
#include <hip/hip_runtime.h>

#define NDIM 28
#define SPAT 784            // 28*28
#define STRIPS 196          // float4 strips per plane
#define NB 256
#define CIN 256
#define COUT 256
#define SCH 4               // Cin split factor
#define CPC (CIN / SCH)     // 64 planes per chunk
#define XSC 36              // LDS halo'd plane row stride (floats)
#define QB 64               // batches per pipeline quarter

typedef float f4v __attribute__((ext_vector_type(4)));

// ---- body of R6's k_sum (proven at read ceiling 7.04 TB/s) ----
__device__ __forceinline__ void dev_sum(const float* __restrict__ x,
                                        float* __restrict__ pbuf,
                                        int b, int chunk, int t) {
    if (t >= STRIPS) return;
    const float4* xp = (const float4*)x
        + ((size_t)b * CIN + (size_t)chunk * CPC) * STRIPS + t;
    float ax = 0.f, ay = 0.f, az = 0.f, aw = 0.f;
    #pragma unroll 16
    for (int c = 0; c < CPC; ++c) {
        float4 v = xp[c * STRIPS];
        ax += v.x; ay += v.y; az += v.z; aw += v.w;
    }
    ((float4*)pbuf)[((size_t)b * SCH + chunk) * STRIPS + t] = make_float4(ax, ay, az, aw);
}

// ---- body of R6's k_conv (nt stores; 4.5 TB/s measured cap) ----
__device__ __forceinline__ void dev_conv(const float* __restrict__ pbuf,
                                         const float* __restrict__ w,
                                         float* __restrict__ out,
                                         float* xs, int b, int cg, int t) {
    if (t < STRIPS) {
        const float4* pp = (const float4*)pbuf + (size_t)b * SCH * STRIPS + t;
        float4 a = pp[0];
        #pragma unroll
        for (int c = 1; c < SCH; ++c) {
            float4 v = pp[c * STRIPS];
            a.x += v.x; a.y += v.y; a.z += v.z; a.w += v.w;
        }
        int i = t / 7, q = t % 7;
        *(float4*)&xs[i * XSC + q * 4] = a;
        if (q == 0)                          // col halo
            *(float4*)&xs[i * XSC + 28] = a;
        if (i < 2) {                         // row halo
            *(float4*)&xs[(i + 28) * XSC + q * 4] = a;
            if (q == 0)
                *(float4*)&xs[(i + 28) * XSC + 28] = a;
        }
    }
    __syncthreads();

    if (t >= STRIPS) return;
    int i  = t / 7;
    int js = (t % 7) * 4;

    float W[3][8];
    #pragma unroll
    for (int a = 0; a < 3; ++a) {
        float4 lo = *(const float4*)&xs[(i + a) * XSC + js];
        float4 hi = *(const float4*)&xs[(i + a) * XSC + js + 4];
        W[a][0] = lo.x; W[a][1] = lo.y; W[a][2] = lo.z; W[a][3] = lo.w;
        W[a][4] = hi.x; W[a][5] = hi.y; W[a][6] = hi.z; W[a][7] = hi.w;
    }

    size_t ob = ((size_t)b * COUT + (size_t)cg * 64) * SPAT + i * NDIM + js;

    #pragma unroll 4
    for (int cl = 0; cl < 64; ++cl) {
        const float* wp = w + (size_t)(cg * 64 + cl) * (CIN * 9);
        float o0 = 0.f, o1 = 0.f, o2 = 0.f, o3 = 0.f;
        #pragma unroll
        for (int a = 0; a < 3; ++a) {
            #pragma unroll
            for (int c = 0; c < 3; ++c) {
                float fv = wp[8 - 3 * a - c];   // w0[co, 2-a, 2-c]
                o0 += fv * W[a][0 + c];
                o1 += fv * W[a][1 + c];
                o2 += fv * W[a][2 + c];
                o3 += fv * W[a][3 + c];
            }
        }
        f4v o = {o0, o1, o2, o3};
        __builtin_nontemporal_store(o, (f4v*)(out + ob + (size_t)cl * SPAT));
    }
}

// quarter sum: 256 blocks, b = b0 + bid>>2, chunk = bid&3
__global__ __launch_bounds__(256) void k_sumq(const float* __restrict__ x,
                                              float* __restrict__ pbuf, int b0) {
    dev_sum(x, pbuf, b0 + (blockIdx.x >> 2), blockIdx.x & 3, threadIdx.x);
}

// quarter conv: 256 blocks
__global__ __launch_bounds__(256) void k_convq(const float* __restrict__ pbuf,
                                               const float* __restrict__ w,
                                               float* __restrict__ out, int b0) {
    __shared__ float xs[30 * XSC];
    dev_conv(pbuf, w, out, xs, b0 + (blockIdx.x >> 2), blockIdx.x & 3, threadIdx.x);
}

// mixed: blocks 0..255 conv quarter bc0 (long pole first), 256..511 sum quarter bs0
__global__ __launch_bounds__(256) void k_mix(const float* __restrict__ x,
                                             float* __restrict__ pbuf,
                                             const float* __restrict__ w,
                                             float* __restrict__ out,
                                             int bs0, int bc0) {
    __shared__ float xs[30 * XSC];
    int bid = blockIdx.x;
    if (bid < 256) {
        dev_conv(pbuf, w, out, xs, bc0 + (bid >> 2), bid & 3, threadIdx.x);
    } else {
        bid -= 256;
        dev_sum(x, pbuf, bs0 + (bid >> 2), bid & 3, threadIdx.x);
    }
}

extern "C" void kernel_launch(void* const* d_in, const int* in_sizes, int n_in,
                              void* d_out, int out_size, void* d_ws, size_t ws_size,
                              hipStream_t stream) {
    const float* x = (const float*)d_in[0];       // (256,256,28,28) f32
    const float* w = (const float*)d_in[1];       // (256,256,3,3) f32
    float* out = (float*)d_out;                   // (256,256,28,28) f32
    float* pbuf = (float*)d_ws;                   // 256*4*784 f32 = 3.2 MB

    // Software pipeline over batch quarters: overlap conv(q) writes with sum(q+1) reads.
    k_sumq <<<256, 256, 0, stream>>>(x, pbuf, 0);
    k_mix  <<<512, 256, 0, stream>>>(x, pbuf, w, out, 1 * QB, 0 * QB);
    k_mix  <<<512, 256, 0, stream>>>(x, pbuf, w, out, 2 * QB, 1 * QB);
    k_mix  <<<512, 256, 0, stream>>>(x, pbuf, w, out, 3 * QB, 2 * QB);
    k_convq<<<256, 256, 0, stream>>>(pbuf, w, out, 3 * QB);
}